// Round 6
// baseline (151.437 us; speedup 1.0000x reference)
//
#include <hip/hip_runtime.h>
#include <stdint.h>

#define BB 8
#define NN 2048
#define KK 32
#define FIN 256
#define FOUT 256
#define CC 512                 // 2*FOUT channels
#define MM (BB*NN)             // 16384 rows
#define RB 32                  // rows per gemm block
#define NBLK (MM/RB)           // 512 gemm blocks
#define LDA 264                // padded LDS row stride (ushorts)

typedef __attribute__((ext_vector_type(8))) short short8;
typedef __attribute__((ext_vector_type(4))) float f32x4;
typedef __attribute__((ext_vector_type(2))) float f32x2;

__device__ __forceinline__ unsigned short f2bf(float f) {
    union { float f; unsigned u; } v; v.f = f;
    unsigned u = v.u;
    return (unsigned short)((u + 0x7FFFu + ((u >> 16) & 1u)) >> 16);  // RNE
}
__device__ __forceinline__ float bf2f(unsigned short s) {
    union { unsigned u; float f; } v; v.u = ((unsigned)s) << 16;
    return v.f;
}
// 2 bf16 in one dword -> float2 {lo, hi}; hi needs no shift (AND only)
__device__ __forceinline__ f32x2 bfpair(unsigned u) {
    union { unsigned u; float f; } lo, hi;
    lo.u = u << 16;
    hi.u = u & 0xFFFF0000u;
    return (f32x2){lo.f, hi.f};
}

// ---------------- K1: W pack (blocks [0,128)) + x->bf16 conv (blocks [128,2176))
// Block 0 additionally zeroes the BN partial slots + last-block counter
// (visible to k_gemm via the dispatch-boundary release).
__global__ void k_prep(const float* __restrict__ Wx, const float* __restrict__ Wxb,
                       const float* __restrict__ Wn, const float* __restrict__ Wnb,
                       const float* __restrict__ x,
                       unsigned short* __restrict__ Wc, float* __restrict__ bc,
                       unsigned short* __restrict__ xb,
                       float* __restrict__ psum8, unsigned* __restrict__ cnt) {
    const int blk = blockIdx.x;
    const int tid = threadIdx.x;
    if (blk < 128) {            // weight pack + bias concat
        if (blk == 0) {         // zero psum8+psq8 (contiguous, CC*16 floats) + cnt
            float4 z = {0.f, 0.f, 0.f, 0.f};
            #pragma unroll
            for (int i = 0; i < (CC * 16 / 4) / 256; ++i)
                ((float4*)psum8)[tid + i * 256] = z;
            if (tid == 0) *cnt = 0u;
        }
        int gid = blk * 256 + tid;                  // 4 elems each
        int e0 = gid * 4;
        int o = e0 >> 8, k = e0 & 255;
        const float* src = (o < FOUT) ? (Wx + o * FIN + k) : (Wn + (o - FOUT) * FIN + k);
        float4 v = *(const float4*)src;
        ushort4 p; p.x = f2bf(v.x); p.y = f2bf(v.y); p.z = f2bf(v.z); p.w = f2bf(v.w);
        *(ushort4*)(Wc + e0) = p;
        if (gid < 128) {
            int c0 = gid * 4;
            float4 bv = (c0 < FOUT) ? *(const float4*)(Wxb + c0)
                                    : *(const float4*)(Wnb + c0 - FOUT);
            *(float4*)(bc + c0) = bv;
        }
    } else {                    // x fp32 -> bf16, 8 elems/thread
        size_t gid = (size_t)(blk - 128) * 256 + tid;
        size_t e0 = gid * 8;
        float4 v0 = *(const float4*)(x + e0);
        float4 v1 = *(const float4*)(x + e0 + 4);
        ushort4 p0, p1;
        p0.x = f2bf(v0.x); p0.y = f2bf(v0.y); p0.z = f2bf(v0.z); p0.w = f2bf(v0.w);
        p1.x = f2bf(v1.x); p1.y = f2bf(v1.y); p1.z = f2bf(v1.z); p1.w = f2bf(v1.w);
        *(ushort4*)(xb + e0)     = p0;
        *(ushort4*)(xb + e0 + 4) = p1;
    }
}

// ---------------- K2: 512 threads (8 waves), RB=32: self-stage + ILP gather-mean
//                  + dual MFMA GEMM + bias + row L2-norm + ReLU + bf16 h
//                  + BN partial atomics into psum8[CC][8] (slot = bid&7).
//                  LAST finishing block (counter) reduces partials -> ss.
__global__ __launch_bounds__(512, 4)
void k_gemm(const unsigned short* __restrict__ xb, const int* __restrict__ idx,
            const unsigned short* __restrict__ Wc,
            const float* __restrict__ bc,
            const float* __restrict__ gamma, const float* __restrict__ beta,
            unsigned short* __restrict__ h,
            float* __restrict__ psum8, float* __restrict__ psq8,
            float* __restrict__ ss, unsigned* __restrict__ cnt) {
    __shared__ unsigned short As[2][RB * LDA];   // [0]=self rows, [1]=neighbor rows
    __shared__ float sqpart[8][RB];
    __shared__ float rnorm[RB];
    __shared__ unsigned lastf;

    const int bid  = blockIdx.x;
    const int tid  = threadIdx.x;
    const int w    = tid >> 6;          // 0..7
    const int lane = tid & 63;
    const int quad = lane >> 4;
    const int l16  = lane & 15;
    const int p    = lane >> 5;         // neighbor parity
    const int l32  = lane & 31;         // 8-channel group
    const int b    = bid & 7;
    const int n0   = (bid >> 3) * RB;
    const unsigned short* xbat = xb + (size_t)b * NN * FIN;
    const size_t r0g = (size_t)b * NN + n0;      // global output row base

    {   // self tile: 32 rows x 256 ch bf16 = 1024 uint4; 512 thr x 2
        const uint4* gs = (const uint4*)(xbat + (size_t)n0 * FIN);
        #pragma unroll
        for (int i = 0; i < 2; ++i) {
            int e = tid + i * 512;               // row=e>>5, col8=e&31
            *(uint4*)&As[0][(e >> 5) * LDA + (e & 31) * 8] = gs[e];
        }
    }
    {   // gather-mean: wave w -> rows w*4..w*4+3; k-outer for cross-row ILP;
        // packed {lo,hi} fp32 accumulation -> v_pk_add_f32
        const int* ip = idx + (n0 + (w << 2)) * KK;    // 4 rows' index lists
        const unsigned short* xp = xbat + l32 * 8;
        f32x2 ac[4][4];                                // [row][pair of channels]
        #pragma unroll
        for (int rr = 0; rr < 4; ++rr)
            #pragma unroll
            for (int c = 0; c < 4; ++c) ac[rr][c] = (f32x2){0.f, 0.f};

        #pragma unroll 4
        for (int k = 0; k < 16; ++k) {
            int kk = (k << 1) | p;
            int j0 = ip[0 * KK + kk];
            int j1 = ip[1 * KK + kk];
            int j2 = ip[2 * KK + kk];
            int j3 = ip[3 * KK + kk];
            uint4 v0 = *(const uint4*)(xp + (size_t)j0 * FIN);
            uint4 v1 = *(const uint4*)(xp + (size_t)j1 * FIN);
            uint4 v2 = *(const uint4*)(xp + (size_t)j2 * FIN);
            uint4 v3 = *(const uint4*)(xp + (size_t)j3 * FIN);
            const unsigned* u0 = (const unsigned*)&v0;
            const unsigned* u1 = (const unsigned*)&v1;
            const unsigned* u2 = (const unsigned*)&v2;
            const unsigned* u3 = (const unsigned*)&v3;
            #pragma unroll
            for (int c = 0; c < 4; ++c) {
                ac[0][c] += bfpair(u0[c]);
                ac[1][c] += bfpair(u1[c]);
                ac[2][c] += bfpair(u2[c]);
                ac[3][c] += bfpair(u3[c]);
            }
        }
        const float s = 1.0f / (float)KK;
        #pragma unroll
        for (int rr = 0; rr < 4; ++rr) {
            #pragma unroll
            for (int c = 0; c < 4; ++c) {
                ac[rr][c][0] += __shfl_xor(ac[rr][c][0], 32, 64);
                ac[rr][c][1] += __shfl_xor(ac[rr][c][1], 32, 64);
            }
            if (p == 0) {
                unsigned short o8[8];
                #pragma unroll
                for (int c = 0; c < 4; ++c) {
                    o8[2 * c]     = f2bf(ac[rr][c][0] * s);   // lo = even channel
                    o8[2 * c + 1] = f2bf(ac[rr][c][1] * s);   // hi = odd channel
                }
                *(uint4*)&As[1][((w << 2) + rr) * LDA + l32 * 8] = *(const uint4*)o8;
            }
        }
    }
    __syncthreads();

    const int half = w >> 2;                     // 0: self, 1: neighbor
    const unsigned short* A = As[half];
    const int cbg = half * 256 + (w & 3) * 64;   // wave's 64 output channels

    f32x4 acc[2][4];
    #pragma unroll
    for (int mt = 0; mt < 2; ++mt)
        #pragma unroll
        for (int nt = 0; nt < 4; ++nt) acc[mt][nt] = (f32x4){0.f, 0.f, 0.f, 0.f};

    const unsigned short* Bp = Wc + (size_t)(cbg + l16) * FIN + quad * 8;  // B^T frag base
    const unsigned short* Ap = A + (size_t)l16 * LDA + quad * 8;

    #pragma unroll 2
    for (int k0 = 0; k0 < FIN; k0 += 32) {
        short8 a0 = *(const short8*)(Ap + k0);
        short8 a1 = *(const short8*)(Ap + 16 * LDA + k0);
        short8 bfr[4];
        #pragma unroll
        for (int nt = 0; nt < 4; ++nt)
            bfr[nt] = *(const short8*)(Bp + (size_t)nt * 16 * FIN + k0);
        #pragma unroll
        for (int nt = 0; nt < 4; ++nt) {
            acc[0][nt] = __builtin_amdgcn_mfma_f32_16x16x32_bf16(a0, bfr[nt], acc[0][nt], 0, 0, 0);
            acc[1][nt] = __builtin_amdgcn_mfma_f32_16x16x32_bf16(a1, bfr[nt], acc[1][nt], 0, 0, 0);
        }
    }

    // bias + per-row sum of squares (C/D layout: col=l16, row=quad*4+reg)
    float bcv[4];
    #pragma unroll
    for (int nt = 0; nt < 4; ++nt) bcv[nt] = bc[cbg + nt * 16 + l16];

    float rsq[2][4] = {{0.f,0.f,0.f,0.f},{0.f,0.f,0.f,0.f}};
    #pragma unroll
    for (int mt = 0; mt < 2; ++mt)
        #pragma unroll
        for (int nt = 0; nt < 4; ++nt)
            #pragma unroll
            for (int r = 0; r < 4; ++r) {
                float v = acc[mt][nt][r] + bcv[nt];
                acc[mt][nt][r] = v;
                rsq[mt][r] += v * v;
            }
    #pragma unroll
    for (int off = 1; off < 16; off <<= 1)
        #pragma unroll
        for (int mt = 0; mt < 2; ++mt)
            #pragma unroll
            for (int r = 0; r < 4; ++r)
                rsq[mt][r] += __shfl_xor(rsq[mt][r], off, 64);
    if (l16 == 0) {
        #pragma unroll
        for (int mt = 0; mt < 2; ++mt)
            #pragma unroll
            for (int r = 0; r < 4; ++r)
                sqpart[w][mt * 16 + quad * 4 + r] = rsq[mt][r];
    }
    __syncthreads();
    if (tid < RB) {
        float tot = 0.f;
        #pragma unroll
        for (int i = 0; i < 8; ++i) tot += sqpart[i][tid];
        rnorm[tid] = 1.0f / fmaxf(sqrtf(tot), 1e-12f);
    }
    __syncthreads();

    // normalize + relu + h store (bf16) + channel partials
    float csum[4] = {0.f,0.f,0.f,0.f};
    float csq [4] = {0.f,0.f,0.f,0.f};
    #pragma unroll
    for (int mt = 0; mt < 2; ++mt) {
        #pragma unroll
        for (int r = 0; r < 4; ++r) {
            int row = mt * 16 + quad * 4 + r;
            float rn = rnorm[row];
            unsigned short* hp = h + (r0g + row) * CC + cbg + l16;
            #pragma unroll
            for (int nt = 0; nt < 4; ++nt) {
                float v = fmaxf(acc[mt][nt][r] * rn, 0.0f);
                hp[nt * 16] = f2bf(v);
                csum[nt] += v;
                csq [nt] += v * v;
            }
        }
    }
    #pragma unroll
    for (int off = 16; off < 64; off <<= 1)
        #pragma unroll
        for (int nt = 0; nt < 4; ++nt) {
            csum[nt] += __shfl_xor(csum[nt], off, 64);
            csq [nt] += __shfl_xor(csq [nt], off, 64);
        }
    if (quad == 0) {   // lanes 0-15: 4 channels each; one add per (c, xcd-slot)
        #pragma unroll
        for (int nt = 0; nt < 4; ++nt) {
            int c = cbg + nt * 16 + l16;
            __hip_atomic_fetch_add(&psum8[c * 8 + b], csum[nt],
                                   __ATOMIC_RELAXED, __HIP_MEMORY_SCOPE_AGENT);
            __hip_atomic_fetch_add(&psq8[c * 8 + b], csq[nt],
                                   __ATOMIC_RELAXED, __HIP_MEMORY_SCOPE_AGENT);
        }
    }

    // ---- last-block-done: the block observing prev==NBLK-1 computes ss.
    __syncthreads();                       // all waves' atomics issued & drained
    if (tid == 0) {
        unsigned prev = __hip_atomic_fetch_add(cnt, 1u, __ATOMIC_ACQ_REL,
                                               __HIP_MEMORY_SCOPE_AGENT);
        lastf = (prev == (unsigned)(NBLK - 1)) ? 1u : 0u;
    }
    __syncthreads();
    if (lastf) {
        if (tid < CC) {                    // thread t -> channel t
            float S = 0.f, Q = 0.f;
            #pragma unroll
            for (int i = 0; i < 8; ++i) {
                S += __hip_atomic_load(&psum8[tid * 8 + i], __ATOMIC_RELAXED,
                                       __HIP_MEMORY_SCOPE_AGENT);
                Q += __hip_atomic_load(&psq8[tid * 8 + i], __ATOMIC_RELAXED,
                                       __HIP_MEMORY_SCOPE_AGENT);
            }
            const float inv = 1.0f / (float)MM;
            float mu  = S * inv;
            float var = fmaxf(Q * inv - mu * mu, 0.0f);
            float sc  = gamma[tid] * rsqrtf(var + 1e-5f);
            ss[tid]      = sc;
            ss[CC + tid] = beta[tid] - mu * sc;
        }
    }
}

// ---------------- K3: BN apply, bf16 h -> fp32 out, 8 elems/thread.
__global__ void k_apply(const unsigned short* __restrict__ h,
                        const float* __restrict__ ss,
                        float* __restrict__ out) {
    const int x   = blockIdx.x & 7;              // batch == XCD
    const int j   = blockIdx.x >> 3;             // 4-row group within batch
    const int tid = threadIdx.x;
    const size_t e0 = (size_t)x * ((size_t)NN * CC) + (size_t)j * 2048 + (size_t)tid * 8;
    int c0 = (int)(e0 & (CC - 1));
    uint4 hv = *(const uint4*)(h + e0);          // 8 bf16
    const unsigned short* hs = (const unsigned short*)&hv;
    float4 sc0 = *(const float4*)(ss + c0);
    float4 sc1 = *(const float4*)(ss + c0 + 4);
    float4 sh0 = *(const float4*)(ss + CC + c0);
    float4 sh1 = *(const float4*)(ss + CC + c0 + 4);
    float4 o0, o1;
    o0.x = bf2f(hs[0]) * sc0.x + sh0.x;
    o0.y = bf2f(hs[1]) * sc0.y + sh0.y;
    o0.z = bf2f(hs[2]) * sc0.z + sh0.z;
    o0.w = bf2f(hs[3]) * sc0.w + sh0.w;
    o1.x = bf2f(hs[4]) * sc1.x + sh1.x;
    o1.y = bf2f(hs[5]) * sc1.y + sh1.y;
    o1.z = bf2f(hs[6]) * sc1.z + sh1.z;
    o1.w = bf2f(hs[7]) * sc1.w + sh1.w;
    *(float4*)(out + e0)     = o0;
    *(float4*)(out + e0 + 4) = o1;
}

extern "C" void kernel_launch(void* const* d_in, const int* in_sizes, int n_in,
                              void* d_out, int out_size, void* d_ws, size_t ws_size,
                              hipStream_t stream) {
    const float* x     = (const float*)d_in[0];
    const int*   idx   = (const int*)  d_in[1];
    const float* Wx_w  = (const float*)d_in[2];
    const float* Wx_b  = (const float*)d_in[3];
    const float* Wn_w  = (const float*)d_in[4];
    const float* Wn_b  = (const float*)d_in[5];
    const float* gamma = (const float*)d_in[6];
    const float* beta  = (const float*)d_in[7];
    float* out = (float*)d_out;

    char* p = (char*)d_ws;
    unsigned short* xb = (unsigned short*)p; p += (size_t)MM * FIN * 2;   // 8.4 MB
    unsigned short* Wc = (unsigned short*)p; p += (size_t)CC * FIN * 2;   // 256 KB
    float* bc          = (float*)p;          p += (size_t)CC * 4;         // 2 KB
    unsigned short* h  = (unsigned short*)p; p += (size_t)MM * CC * 2;    // 16.8 MB
    float* psum8       = (float*)p;          p += (size_t)CC * 8 * 4;     // 16 KB
    float* psq8        = (float*)p;          p += (size_t)CC * 8 * 4;     // 16 KB (contiguous after psum8)
    float* ss          = (float*)p;          p += (size_t)2 * CC * 4;     // 4 KB
    unsigned* cnt      = (unsigned*)p;       p += 64;                     // counter

    hipLaunchKernelGGL(k_prep,  dim3(2176), dim3(256), 0, stream,
                       Wx_w, Wx_b, Wn_w, Wn_b, x, Wc, bc, xb, psum8, cnt);
    hipLaunchKernelGGL(k_gemm,  dim3(NBLK), dim3(512), 0, stream,
                       xb, idx, Wc, bc, gamma, beta, h, psum8, psq8, ss, cnt);
    hipLaunchKernelGGL(k_apply, dim3(4096), dim3(256), 0, stream, h, ss, out);
}

// Round 7
// 135.282 us; speedup vs baseline: 1.1194x; 1.1194x over previous
//
#include <hip/hip_runtime.h>
#include <stdint.h>

#define BB 8
#define NN 2048
#define KK 32
#define FIN 256
#define FOUT 256
#define CC 512                 // 2*FOUT channels
#define MM (BB*NN)             // 16384 rows
#define RB 32                  // rows per gemm block
#define NBLK (MM/RB)           // 512 gemm blocks
#define LDA 264                // padded LDS row stride (ushorts)

typedef __attribute__((ext_vector_type(8))) short short8;
typedef __attribute__((ext_vector_type(4))) float f32x4;
typedef __attribute__((ext_vector_type(2))) float f32x2;

__device__ __forceinline__ unsigned short f2bf(float f) {
    union { float f; unsigned u; } v; v.f = f;
    unsigned u = v.u;
    return (unsigned short)((u + 0x7FFFu + ((u >> 16) & 1u)) >> 16);  // RNE
}
__device__ __forceinline__ float bf2f(unsigned short s) {
    union { unsigned u; float f; } v; v.u = ((unsigned)s) << 16;
    return v.f;
}
// 2 bf16 in one dword -> float2 {lo, hi}; hi needs no shift (AND only)
__device__ __forceinline__ f32x2 bfpair(unsigned u) {
    union { unsigned u; float f; } lo, hi;
    lo.u = u << 16;
    hi.u = u & 0xFFFF0000u;
    return (f32x2){lo.f, hi.f};
}

// ---------------- K1: W pack (blocks [0,128)) + x->bf16 conv (blocks [128,2176))
// Block 0 additionally zeroes the BN partial slots (psum8+psq8, 32 KB).
__global__ void k_prep(const float* __restrict__ Wx, const float* __restrict__ Wxb,
                       const float* __restrict__ Wn, const float* __restrict__ Wnb,
                       const float* __restrict__ x,
                       unsigned short* __restrict__ Wc, float* __restrict__ bc,
                       unsigned short* __restrict__ xb,
                       float* __restrict__ psum8) {
    const int blk = blockIdx.x;
    const int tid = threadIdx.x;
    if (blk < 128) {            // weight pack + bias concat
        if (blk == 0) {         // zero psum8+psq8 (contiguous, CC*16 floats)
            float4 z = {0.f, 0.f, 0.f, 0.f};
            #pragma unroll
            for (int i = 0; i < (CC * 16 / 4) / 256; ++i)
                ((float4*)psum8)[tid + i * 256] = z;
        }
        int gid = blk * 256 + tid;                  // 4 elems each
        int e0 = gid * 4;
        int o = e0 >> 8, k = e0 & 255;
        const float* src = (o < FOUT) ? (Wx + o * FIN + k) : (Wn + (o - FOUT) * FIN + k);
        float4 v = *(const float4*)src;
        ushort4 p; p.x = f2bf(v.x); p.y = f2bf(v.y); p.z = f2bf(v.z); p.w = f2bf(v.w);
        *(ushort4*)(Wc + e0) = p;
        if (gid < 128) {
            int c0 = gid * 4;
            float4 bv = (c0 < FOUT) ? *(const float4*)(Wxb + c0)
                                    : *(const float4*)(Wnb + c0 - FOUT);
            *(float4*)(bc + c0) = bv;
        }
    } else {                    // x fp32 -> bf16, 8 elems/thread
        size_t gid = (size_t)(blk - 128) * 256 + tid;
        size_t e0 = gid * 8;
        float4 v0 = *(const float4*)(x + e0);
        float4 v1 = *(const float4*)(x + e0 + 4);
        ushort4 p0, p1;
        p0.x = f2bf(v0.x); p0.y = f2bf(v0.y); p0.z = f2bf(v0.z); p0.w = f2bf(v0.w);
        p1.x = f2bf(v1.x); p1.y = f2bf(v1.y); p1.z = f2bf(v1.z); p1.w = f2bf(v1.w);
        *(ushort4*)(xb + e0)     = p0;
        *(ushort4*)(xb + e0 + 4) = p1;
    }
}

// ---------------- K2: 512 threads (8 waves), RB=32: self-stage + ILP gather-mean
//                  + dual MFMA GEMM + bias + row L2-norm + ReLU + bf16 h
//                  + BN partial atomics into SLOT-MAJOR psum8[8][CC] (slot =
//                  bid&7): each XCD's blocks hit a private 2 KB region -> no
//                  cross-XCD line sharing; relaxed no-return adds -> no stall.
__global__ __launch_bounds__(512, 4)
void k_gemm(const unsigned short* __restrict__ xb, const int* __restrict__ idx,
            const unsigned short* __restrict__ Wc,
            const float* __restrict__ bc,
            unsigned short* __restrict__ h,
            float* __restrict__ psum8, float* __restrict__ psq8) {
    __shared__ unsigned short As[2][RB * LDA];   // [0]=self rows, [1]=neighbor rows
    __shared__ float sqpart[8][RB];
    __shared__ float rnorm[RB];

    const int bid  = blockIdx.x;
    const int tid  = threadIdx.x;
    const int w    = tid >> 6;          // 0..7
    const int lane = tid & 63;
    const int quad = lane >> 4;
    const int l16  = lane & 15;
    const int p    = lane >> 5;         // neighbor parity
    const int l32  = lane & 31;         // 8-channel group
    const int b    = bid & 7;
    const int n0   = (bid >> 3) * RB;
    const unsigned short* xbat = xb + (size_t)b * NN * FIN;
    const size_t r0g = (size_t)b * NN + n0;      // global output row base

    {   // self tile: 32 rows x 256 ch bf16 = 1024 uint4; 512 thr x 2
        const uint4* gs = (const uint4*)(xbat + (size_t)n0 * FIN);
        #pragma unroll
        for (int i = 0; i < 2; ++i) {
            int e = tid + i * 512;               // row=e>>5, col8=e&31
            *(uint4*)&As[0][(e >> 5) * LDA + (e & 31) * 8] = gs[e];
        }
    }
    {   // gather-mean: wave w -> rows w*4..w*4+3; k-outer for cross-row ILP;
        // packed {lo,hi} fp32 accumulation -> v_pk_add_f32
        const int* ip = idx + (n0 + (w << 2)) * KK;    // 4 rows' index lists
        const unsigned short* xp = xbat + l32 * 8;
        f32x2 ac[4][4];                                // [row][pair of channels]
        #pragma unroll
        for (int rr = 0; rr < 4; ++rr)
            #pragma unroll
            for (int c = 0; c < 4; ++c) ac[rr][c] = (f32x2){0.f, 0.f};

        #pragma unroll 2
        for (int k = 0; k < 16; ++k) {
            int kk = (k << 1) | p;
            int j0 = ip[0 * KK + kk];
            int j1 = ip[1 * KK + kk];
            int j2 = ip[2 * KK + kk];
            int j3 = ip[3 * KK + kk];
            uint4 v0 = *(const uint4*)(xp + (size_t)j0 * FIN);
            uint4 v1 = *(const uint4*)(xp + (size_t)j1 * FIN);
            uint4 v2 = *(const uint4*)(xp + (size_t)j2 * FIN);
            uint4 v3 = *(const uint4*)(xp + (size_t)j3 * FIN);
            const unsigned* u0 = (const unsigned*)&v0;
            const unsigned* u1 = (const unsigned*)&v1;
            const unsigned* u2 = (const unsigned*)&v2;
            const unsigned* u3 = (const unsigned*)&v3;
            #pragma unroll
            for (int c = 0; c < 4; ++c) {
                ac[0][c] += bfpair(u0[c]);
                ac[1][c] += bfpair(u1[c]);
                ac[2][c] += bfpair(u2[c]);
                ac[3][c] += bfpair(u3[c]);
            }
        }
        const float s = 1.0f / (float)KK;
        #pragma unroll
        for (int rr = 0; rr < 4; ++rr) {
            #pragma unroll
            for (int c = 0; c < 4; ++c) {
                ac[rr][c][0] += __shfl_xor(ac[rr][c][0], 32, 64);
                ac[rr][c][1] += __shfl_xor(ac[rr][c][1], 32, 64);
            }
            if (p == 0) {
                unsigned short o8[8];
                #pragma unroll
                for (int c = 0; c < 4; ++c) {
                    o8[2 * c]     = f2bf(ac[rr][c][0] * s);   // lo = even channel
                    o8[2 * c + 1] = f2bf(ac[rr][c][1] * s);   // hi = odd channel
                }
                *(uint4*)&As[1][((w << 2) + rr) * LDA + l32 * 8] = *(const uint4*)o8;
            }
        }
    }
    __syncthreads();

    const int half = w >> 2;                     // 0: self, 1: neighbor
    const unsigned short* A = As[half];
    const int cbg = half * 256 + (w & 3) * 64;   // wave's 64 output channels

    f32x4 acc[2][4];
    #pragma unroll
    for (int mt = 0; mt < 2; ++mt)
        #pragma unroll
        for (int nt = 0; nt < 4; ++nt) acc[mt][nt] = (f32x4){0.f, 0.f, 0.f, 0.f};

    const unsigned short* Bp = Wc + (size_t)(cbg + l16) * FIN + quad * 8;  // B^T frag base
    const unsigned short* Ap = A + (size_t)l16 * LDA + quad * 8;

    #pragma unroll 2
    for (int k0 = 0; k0 < FIN; k0 += 32) {
        short8 a0 = *(const short8*)(Ap + k0);
        short8 a1 = *(const short8*)(Ap + 16 * LDA + k0);
        short8 bfr[4];
        #pragma unroll
        for (int nt = 0; nt < 4; ++nt)
            bfr[nt] = *(const short8*)(Bp + (size_t)nt * 16 * FIN + k0);
        #pragma unroll
        for (int nt = 0; nt < 4; ++nt) {
            acc[0][nt] = __builtin_amdgcn_mfma_f32_16x16x32_bf16(a0, bfr[nt], acc[0][nt], 0, 0, 0);
            acc[1][nt] = __builtin_amdgcn_mfma_f32_16x16x32_bf16(a1, bfr[nt], acc[1][nt], 0, 0, 0);
        }
    }

    // bias + per-row sum of squares (C/D layout: col=l16, row=quad*4+reg)
    float bcv[4];
    #pragma unroll
    for (int nt = 0; nt < 4; ++nt) bcv[nt] = bc[cbg + nt * 16 + l16];

    float rsq[2][4] = {{0.f,0.f,0.f,0.f},{0.f,0.f,0.f,0.f}};
    #pragma unroll
    for (int mt = 0; mt < 2; ++mt)
        #pragma unroll
        for (int nt = 0; nt < 4; ++nt)
            #pragma unroll
            for (int r = 0; r < 4; ++r) {
                float v = acc[mt][nt][r] + bcv[nt];
                acc[mt][nt][r] = v;
                rsq[mt][r] += v * v;
            }
    #pragma unroll
    for (int off = 1; off < 16; off <<= 1)
        #pragma unroll
        for (int mt = 0; mt < 2; ++mt)
            #pragma unroll
            for (int r = 0; r < 4; ++r)
                rsq[mt][r] += __shfl_xor(rsq[mt][r], off, 64);
    if (l16 == 0) {
        #pragma unroll
        for (int mt = 0; mt < 2; ++mt)
            #pragma unroll
            for (int r = 0; r < 4; ++r)
                sqpart[w][mt * 16 + quad * 4 + r] = rsq[mt][r];
    }
    __syncthreads();
    if (tid < RB) {
        float tot = 0.f;
        #pragma unroll
        for (int i = 0; i < 8; ++i) tot += sqpart[i][tid];
        rnorm[tid] = 1.0f / fmaxf(sqrtf(tot), 1e-12f);
    }
    __syncthreads();

    // normalize + relu + h store (bf16) + channel partials
    float csum[4] = {0.f,0.f,0.f,0.f};
    float csq [4] = {0.f,0.f,0.f,0.f};
    #pragma unroll
    for (int mt = 0; mt < 2; ++mt) {
        #pragma unroll
        for (int r = 0; r < 4; ++r) {
            int row = mt * 16 + quad * 4 + r;
            float rn = rnorm[row];
            unsigned short* hp = h + (r0g + row) * CC + cbg + l16;
            #pragma unroll
            for (int nt = 0; nt < 4; ++nt) {
                float v = fmaxf(acc[mt][nt][r] * rn, 0.0f);
                hp[nt * 16] = f2bf(v);
                csum[nt] += v;
                csq [nt] += v * v;
            }
        }
    }
    #pragma unroll
    for (int off = 16; off < 64; off <<= 1)
        #pragma unroll
        for (int nt = 0; nt < 4; ++nt) {
            csum[nt] += __shfl_xor(csum[nt], off, 64);
            csq [nt] += __shfl_xor(csq [nt], off, 64);
        }
    if (quad == 0) {   // lanes 0-15: 4 channels each; relaxed fire-and-forget
        #pragma unroll
        for (int nt = 0; nt < 4; ++nt) {
            int c = cbg + nt * 16 + l16;
            __hip_atomic_fetch_add(&psum8[b * CC + c], csum[nt],
                                   __ATOMIC_RELAXED, __HIP_MEMORY_SCOPE_AGENT);
            __hip_atomic_fetch_add(&psq8[b * CC + c], csq[nt],
                                   __ATOMIC_RELAXED, __HIP_MEMORY_SCOPE_AGENT);
        }
    }
}

// ---------------- K3: BN stats (per-block from 32 KB partial table, in LDS)
//                  + apply, bf16 h -> fp32 out, 8 elems/thread.
// Stats recompute per block: 32 KB L2-resident reads, deterministic order ->
// identical ss in every block. Padded LDS index c+(c>>3) spreads the stride-8
// channel access across all 32 banks.
__global__ __launch_bounds__(256)
void k_apply(const unsigned short* __restrict__ h,
             const float* __restrict__ psum8, const float* __restrict__ psq8,
             const float* __restrict__ gamma, const float* __restrict__ beta,
             float* __restrict__ out) {
    __shared__ float ssc[CC + (CC >> 3)];
    __shared__ float ssh[CC + (CC >> 3)];
    const int tid = threadIdx.x;
    {   // thread t -> channels 2t, 2t+1
        const int c = tid * 2;
        float2 S = {0.f, 0.f}, Q = {0.f, 0.f};
        #pragma unroll
        for (int i = 0; i < 8; ++i) {
            float2 a = *(const float2*)(psum8 + i * CC + c);
            float2 b = *(const float2*)(psq8  + i * CC + c);
            S.x += a.x; S.y += a.y; Q.x += b.x; Q.y += b.y;
        }
        const float inv = 1.0f / (float)MM;
        float2 g  = *(const float2*)(gamma + c);
        float2 be = *(const float2*)(beta + c);
        float mu0 = S.x * inv, mu1 = S.y * inv;
        float v0 = fmaxf(Q.x * inv - mu0 * mu0, 0.0f);
        float v1 = fmaxf(Q.y * inv - mu1 * mu1, 0.0f);
        float sc0 = g.x * rsqrtf(v0 + 1e-5f);
        float sc1 = g.y * rsqrtf(v1 + 1e-5f);
        int pc = c + (c >> 3);
        ssc[pc]     = sc0; ssc[pc + 1] = sc1;
        ssh[pc]     = be.x - mu0 * sc0;
        ssh[pc + 1] = be.y - mu1 * sc1;
    }
    __syncthreads();

    const int x = blockIdx.x & 7;                // batch == XCD
    const int j = blockIdx.x >> 3;               // 4-row group within batch
    const size_t e0 = (size_t)x * ((size_t)NN * CC) + (size_t)j * 2048 + (size_t)tid * 8;
    const int c0 = (int)(e0 & (CC - 1));
    const int pb = c0 + (c0 >> 3);               // padded LDS base (c0 % 8 == 0)
    uint4 hv = *(const uint4*)(h + e0);          // 8 bf16
    const unsigned short* hs = (const unsigned short*)&hv;
    float4 o0, o1;
    o0.x = bf2f(hs[0]) * ssc[pb + 0] + ssh[pb + 0];
    o0.y = bf2f(hs[1]) * ssc[pb + 1] + ssh[pb + 1];
    o0.z = bf2f(hs[2]) * ssc[pb + 2] + ssh[pb + 2];
    o0.w = bf2f(hs[3]) * ssc[pb + 3] + ssh[pb + 3];
    o1.x = bf2f(hs[4]) * ssc[pb + 4] + ssh[pb + 4];
    o1.y = bf2f(hs[5]) * ssc[pb + 5] + ssh[pb + 5];
    o1.z = bf2f(hs[6]) * ssc[pb + 6] + ssh[pb + 6];
    o1.w = bf2f(hs[7]) * ssc[pb + 7] + ssh[pb + 7];
    *(float4*)(out + e0)     = o0;
    *(float4*)(out + e0 + 4) = o1;
}

extern "C" void kernel_launch(void* const* d_in, const int* in_sizes, int n_in,
                              void* d_out, int out_size, void* d_ws, size_t ws_size,
                              hipStream_t stream) {
    const float* x     = (const float*)d_in[0];
    const int*   idx   = (const int*)  d_in[1];
    const float* Wx_w  = (const float*)d_in[2];
    const float* Wx_b  = (const float*)d_in[3];
    const float* Wn_w  = (const float*)d_in[4];
    const float* Wn_b  = (const float*)d_in[5];
    const float* gamma = (const float*)d_in[6];
    const float* beta  = (const float*)d_in[7];
    float* out = (float*)d_out;

    char* p = (char*)d_ws;
    unsigned short* xb = (unsigned short*)p; p += (size_t)MM * FIN * 2;   // 8.4 MB
    unsigned short* Wc = (unsigned short*)p; p += (size_t)CC * FIN * 2;   // 256 KB
    float* bc          = (float*)p;          p += (size_t)CC * 4;         // 2 KB
    unsigned short* h  = (unsigned short*)p; p += (size_t)MM * CC * 2;    // 16.8 MB
    float* psum8       = (float*)p;          p += (size_t)8 * CC * 4;     // 16 KB (slot-major)
    float* psq8        = (float*)p;          p += (size_t)8 * CC * 4;     // 16 KB (contiguous after psum8)

    hipLaunchKernelGGL(k_prep,  dim3(2176), dim3(256), 0, stream,
                       Wx_w, Wx_b, Wn_w, Wn_b, x, Wc, bc, xb, psum8);
    hipLaunchKernelGGL(k_gemm,  dim3(NBLK), dim3(512), 0, stream,
                       xb, idx, Wc, bc, h, psum8, psq8);
    hipLaunchKernelGGL(k_apply, dim3(4096), dim3(256), 0, stream,
                       h, psum8, psq8, gamma, beta, out);
}